// Round 8
// baseline (145.553 us; speedup 1.0000x reference)
//
#include <hip/hip_runtime.h>
#include <math.h>

// ===== ROUND 8: ALGEBRAIC REFACTOR — commute W through the aggregation =====
// agg[n] = (sum s~ * emb[dst]) @ W + b_scale   (sum s~ = 1), and the attention
// scalars are emb . (W @ ws|wd) + const. So the 50k x 128 x 128 GEMM moves
// AFTER the gather (operating on L3-warm data), and the gather reads emb_bf
// instead of item (same bytes). Pipeline:
//   k_pre: WT transpose + u_src/u_dst/c + rowptr   (1 small launch)
//   k_att: a_src/a_dst (f32 dots) + emb_bf copy    (pure stream, ~6 us)
//   k_agg: same gather structure -> aggN bf16      (12.8 MB write, was 25.6)
//   k_out: aggN @ W + b_scale -> sigmoid -> out    (lean GEMM, warm input)

#define NN 50001
#define DD 128
#define NE 800000
#define EDGE_BLOCKS 3125             // ceil(800000/256)
#define ATT_BLOCKS 3126              // ceil(50001/16)
#define OUT_BLOCKS 782               // ceil(ceil(50001/16)/4)
#define TR_BLOCKS 64                 // transpose blocks (2 cols each)

typedef __attribute__((ext_vector_type(8))) short short8;
typedef __attribute__((ext_vector_type(4))) float floatx4;

__device__ __forceinline__ unsigned short f2bf(float f) {
    unsigned u = __builtin_bit_cast(unsigned, f);
    u += 0x7fffu + ((u >> 16) & 1u);          // round-to-nearest-even
    return (unsigned short)(u >> 16);
}
__device__ __forceinline__ float bflo(unsigned u) {   // low 16 bits as bf16 -> f32
    return __builtin_bit_cast(float, u << 16);
}
__device__ __forceinline__ float bfhi(unsigned u) {   // high 16 bits as bf16 -> f32
    return __builtin_bit_cast(float, u & 0xffff0000u);
}
__device__ __forceinline__ float score(float att) {   // leaky-relu(0.2) then exp(x-1)
    att = att >= 0.f ? att : 0.2f * att;
    return __expf(att - 1.f);
}

// K0: bx<64: WT[j][k]=bf16(W[k][j]); bx==64: u/c compute; bx>64: rowptr.
__global__ void __launch_bounds__(256) k_pre(const float* __restrict__ W,
        const float* __restrict__ W_att, const float* __restrict__ b_scale,
        const float* __restrict__ b_att, const int* __restrict__ edge,
        unsigned short* __restrict__ WT, float* __restrict__ u_src,
        float* __restrict__ u_dst, float* __restrict__ cb,
        int* __restrict__ row_ptr) {
    if (blockIdx.x < TR_BLOCKS) {
        int j = blockIdx.x * 2 + (threadIdx.x >> 7);    // feature column
        int k = threadIdx.x & 127;                      // contraction index
        WT[j * DD + k] = f2bf(W[k * DD + j]);
        return;
    }
    if (blockIdx.x == TR_BLOCKS) {                      // u_src/u_dst/c (tiny)
        int k = threadIdx.x;
        if (k < DD) {
            float us = 0.f, ud = 0.f;
            for (int j = 0; j < DD; j++) {
                float w = W[k * DD + j];
                us += w * W_att[j];
                ud += w * W_att[DD + j];
            }
            u_src[k] = us; u_dst[k] = ud;
        } else if (k == DD) {
            float c = b_att[0];
            for (int j = 0; j < DD; j++) c += b_scale[j] * W_att[j];
            cb[0] = c;
        } else if (k == DD + 1) {
            float c = 0.f;
            for (int j = 0; j < DD; j++) c += b_scale[j] * W_att[DD + j];
            cb[1] = c;
        }
        return;
    }
    int e = (blockIdx.x - TR_BLOCKS - 1) * 256 + threadIdx.x;
    if (e >= NE) return;
    int s = edge[2 * e];
    if (e == 0) {
        for (int n = 0; n <= s; n++) row_ptr[n] = 0;
    } else {
        int p = edge[2 * (e - 1)];
        for (int n = p + 1; n <= s; n++) row_ptr[n] = e;
    }
    if (e == NE - 1) {
        for (int n = s + 1; n <= NN; n++) row_ptr[n] = NE;
    }
}

// K1: one 16-lane group per node. a_src[n]=emb[n].u_src+c0, a_dst=emb.u_dst+c1,
// and emb_bf[n] = bf16(emb[n]). Pure stream of emb (25.6 MB), fully coalesced.
__global__ void __launch_bounds__(256) k_att(const float* __restrict__ emb,
        const float* __restrict__ u_src, const float* __restrict__ u_dst,
        const float* __restrict__ cb, unsigned short* __restrict__ emb_bf,
        float* __restrict__ a_src, float* __restrict__ a_dst) {
    int n = blockIdx.x * 16 + (threadIdx.x >> 4);
    int t = threadIdx.x & 15;
    if (n >= NN) return;

    const float* ep = emb + (long)n * DD + t * 8;
    float4 e0 = *(const float4*)(ep);
    float4 e1 = *(const float4*)(ep + 4);
    float4 us0 = *(const float4*)(u_src + t * 8);
    float4 us1 = *(const float4*)(u_src + t * 8 + 4);
    float4 ud0 = *(const float4*)(u_dst + t * 8);
    float4 ud1 = *(const float4*)(u_dst + t * 8 + 4);

    float ps = e0.x * us0.x + e0.y * us0.y + e0.z * us0.z + e0.w * us0.w
             + e1.x * us1.x + e1.y * us1.y + e1.z * us1.z + e1.w * us1.w;
    float pd = e0.x * ud0.x + e0.y * ud0.y + e0.z * ud0.z + e0.w * ud0.w
             + e1.x * ud1.x + e1.y * ud1.y + e1.z * ud1.z + e1.w * ud1.w;

    uint4 pk;
    pk.x = (unsigned)f2bf(e0.x) | ((unsigned)f2bf(e0.y) << 16);
    pk.y = (unsigned)f2bf(e0.z) | ((unsigned)f2bf(e0.w) << 16);
    pk.z = (unsigned)f2bf(e1.x) | ((unsigned)f2bf(e1.y) << 16);
    pk.w = (unsigned)f2bf(e1.z) | ((unsigned)f2bf(e1.w) << 16);
    *(uint4*)(emb_bf + (long)n * DD + t * 8) = pk;

    ps += __shfl_xor(ps, 1, 16); ps += __shfl_xor(ps, 2, 16);
    ps += __shfl_xor(ps, 4, 16); ps += __shfl_xor(ps, 8, 16);
    pd += __shfl_xor(pd, 1, 16); pd += __shfl_xor(pd, 2, 16);
    pd += __shfl_xor(pd, 4, 16); pd += __shfl_xor(pd, 8, 16);
    if (t == 0) { a_src[n] = ps + cb[0]; a_dst[n] = pd + cb[1]; }
}

// K2: gather/aggregate (structure identical to R1), over emb_bf; emits
// normalized bf16 agg rows.
#define ACC8(S, U) \
    acc[0] += (S) * bflo((U).x); acc[1] += (S) * bfhi((U).x); \
    acc[2] += (S) * bflo((U).y); acc[3] += (S) * bfhi((U).y); \
    acc[4] += (S) * bflo((U).z); acc[5] += (S) * bfhi((U).z); \
    acc[6] += (S) * bflo((U).w); acc[7] += (S) * bfhi((U).w);

__global__ void __launch_bounds__(256) k_agg(const int* __restrict__ edge,
        const int* __restrict__ row_ptr, const unsigned short* __restrict__ emb_bf,
        const float* __restrict__ a_src, const float* __restrict__ a_dst,
        unsigned short* __restrict__ aggN) {
    int n = blockIdx.x * 16 + (threadIdx.x >> 4);
    int t = threadIdx.x & 15;
    if (n >= NN) return;

    int start = row_ptr[n];
    int len = row_ptr[n + 1] - start;
    unsigned short* op = aggN + (long)n * DD + t * 8;

    if (len <= 0) {
        uint4 z = make_uint4(0u, 0u, 0u, 0u);            // agg = 0 (k_out -> 0.5)
        *(uint4*)op = z;
        return;
    }

    float asrc = a_src[n];                 // c_src (incl. b_att) folded in
    const int* dp = edge + 2 * start + 1;  // dst stream, stride-2 ints
    const unsigned short* ip = emb_bf + t * 8;

    float acc[8] = {0.f, 0.f, 0.f, 0.f, 0.f, 0.f, 0.f, 0.f};
    float ssum = 0.f;

    for (int j = 0; j < len; j += 16) {
        int jj = j + t;
        int idx = jj < len ? jj : len - 1;
        int d = dp[2 * idx];               // 16 lanes, contiguous 128 B window
        float x = a_dst[d];                // scattered 4 B, L2-resident (200 KB)
        float s = (jj < len) ? score(asrc + x) : 0.f;
        ssum += s;

        int cnt = len - j;
        if (cnt > 16) cnt = 16;
        int kk = 0;
        for (; kk + 4 <= cnt; kk += 4) {
            int d0 = __shfl(d, kk, 16),     d1 = __shfl(d, kk + 1, 16);
            int d2 = __shfl(d, kk + 2, 16), d3 = __shfl(d, kk + 3, 16);
            float s0 = __shfl(s, kk, 16),     s1 = __shfl(s, kk + 1, 16);
            float s2 = __shfl(s, kk + 2, 16), s3 = __shfl(s, kk + 3, 16);
            uint4 u0 = *(const uint4*)(ip + (long)d0 * DD);
            uint4 u1 = *(const uint4*)(ip + (long)d1 * DD);
            uint4 u2 = *(const uint4*)(ip + (long)d2 * DD);
            uint4 u3 = *(const uint4*)(ip + (long)d3 * DD);
            ACC8(s0, u0);
            ACC8(s1, u1);
            ACC8(s2, u2);
            ACC8(s3, u3);
        }
        for (; kk < cnt; kk++) {
            int d0 = __shfl(d, kk, 16);
            float s0 = __shfl(s, kk, 16);
            uint4 u0 = *(const uint4*)(ip + (long)d0 * DD);
            ACC8(s0, u0);
        }
    }

    ssum += __shfl_xor(ssum, 1, 16);
    ssum += __shfl_xor(ssum, 2, 16);
    ssum += __shfl_xor(ssum, 4, 16);
    ssum += __shfl_xor(ssum, 8, 16);
    float inv = 1.f / ssum;

    uint4 pk;
    pk.x = (unsigned)f2bf(acc[0] * inv) | ((unsigned)f2bf(acc[1] * inv) << 16);
    pk.y = (unsigned)f2bf(acc[2] * inv) | ((unsigned)f2bf(acc[3] * inv) << 16);
    pk.z = (unsigned)f2bf(acc[4] * inv) | ((unsigned)f2bf(acc[5] * inv) << 16);
    pk.w = (unsigned)f2bf(acc[6] * inv) | ((unsigned)f2bf(acc[7] * inv) << 16);
    *(uint4*)op = pk;
}

// K3: out = sigmoid(aggN @ W + b_scale); empty nodes -> 0.5. One wave per 16
// nodes; B-frags load directly as bf16 (no conversion); A-frags from WT.
__global__ void __launch_bounds__(256) k_out(const unsigned short* __restrict__ aggN,
        const unsigned short* __restrict__ WT, const float* __restrict__ b_scale,
        const int* __restrict__ row_ptr, float* __restrict__ out) {
    int wave = blockIdx.x * 4 + (threadIdx.x >> 6);
    int lane = threadIdx.x & 63;
    int base = wave * 16;
    if (base >= NN) return;
    int m = lane & 15, q = lane >> 4;
    int node = base + m;
    bool valid = node < NN;
    int row = valid ? node : NN - 1;
    int len = row_ptr[row + 1] - row_ptr[row];

    const unsigned short* bp = aggN + (long)row * DD + q * 8;
    short8 b[4];
    #pragma unroll
    for (int ks = 0; ks < 4; ks++)
        b[ks] = *(const short8*)(bp + ks * 32);

    #pragma unroll
    for (int ft = 0; ft < 8; ft++) {
        floatx4 acc = {0.f, 0.f, 0.f, 0.f};
        const unsigned short* wrow = WT + (ft * 16 + m) * DD + q * 8;
        #pragma unroll
        for (int ks = 0; ks < 4; ks++) {
            short8 a = *(const short8*)(wrow + ks * 32);
            acc = __builtin_amdgcn_mfma_f32_16x16x32_bf16(a, b[ks], acc, 0, 0, 0);
        }
        if (valid) {
            int fo = ft * 16 + q * 4;
            float4 bs = *(const float4*)(b_scale + fo);
            float4 o;
            if (len > 0) {
                o.x = 1.f / (1.f + __expf(-(acc[0] + bs.x)));
                o.y = 1.f / (1.f + __expf(-(acc[1] + bs.y)));
                o.z = 1.f / (1.f + __expf(-(acc[2] + bs.z)));
                o.w = 1.f / (1.f + __expf(-(acc[3] + bs.w)));
            } else {
                o = make_float4(0.5f, 0.5f, 0.5f, 0.5f);
            }
            *(float4*)(out + (long)node * DD + fo) = o;
        }
    }
}

extern "C" void kernel_launch(void* const* d_in, const int* in_sizes, int n_in,
                              void* d_out, int out_size, void* d_ws, size_t ws_size,
                              hipStream_t stream) {
    const int*   edge    = (const int*)d_in[0];
    const float* emb     = (const float*)d_in[1];
    const float* W_scale = (const float*)d_in[2];
    const float* b_scale = (const float*)d_in[3];
    const float* W_att   = (const float*)d_in[4];
    const float* b_att   = (const float*)d_in[5];
    float* out = (float*)d_out;

    char* ws = (char*)d_ws;
    int*            row_ptr = (int*)(ws);                                // 200832 B
    float*          a_src   = (float*)(ws + 200832);                     // 200192 B
    float*          a_dst   = (float*)(ws + 401024);                     // 200192 B
    unsigned short* emb_bf  = (unsigned short*)(ws + 601216);            // 12800256 B
    unsigned short* aggN    = (unsigned short*)(ws + 13401472);          // 12800256 B
    unsigned short* WT      = (unsigned short*)(ws + 26201728);          // 32768 B
    float*          u_src   = (float*)(ws + 26234496);                   // 512 B
    float*          u_dst   = (float*)(ws + 26235008);                   // 512 B
    float*          cb      = (float*)(ws + 26235520);                   // 8 B

    k_pre <<<TR_BLOCKS + 1 + EDGE_BLOCKS, 256, 0, stream>>>(W_scale, W_att, b_scale,
                                                            b_att, edge, WT, u_src,
                                                            u_dst, cb, row_ptr);
    k_att <<<ATT_BLOCKS,  256, 0, stream>>>(emb, u_src, u_dst, cb, emb_bf,
                                            a_src, a_dst);
    k_agg <<<ATT_BLOCKS,  256, 0, stream>>>(edge, row_ptr, emb_bf, a_src, a_dst,
                                            aggN);
    k_out <<<OUT_BLOCKS,  256, 0, stream>>>(aggN, WT, b_scale, row_ptr, out);
}

// Round 9
// 141.031 us; speedup vs baseline: 1.0321x; 1.0321x over previous
//
#include <hip/hip_runtime.h>
#include <math.h>

// ===== ROUND 9: FUSE out-GEMM INTO GATHER KERNEL =====
// Ledger (R2/R3/R5): floor~71, Tg~21, Ta~37; R8 k_out ~26. Every 782-block
// wave-per-16-node MFMA kernel costs 20-30us (3 waves/SIMD, latency-bound).
// Fix: k_agg's 3126-block shape (48 waves/CU) already owns 16 nodes/block =
// one MFMA tile -> do the aggN @ W + sigmoid right there via 4.3KB LDS tile,
// ft-split across the block's 4 waves. Deletes k_out launch + 25.6MB aggN
// roundtrip. Numerics bit-identical to R8 (absmax should stay 0.001953125).
//   k_pre: WT transpose + u_src/u_dst/cb + rowptr
//   k_att: a_src/a_dst dots + emb_bf  (unchanged from R8)
//   k_fused: gather (8-deep unroll) -> LDS bf16 agg -> MFMA -> sigmoid -> out

#define NN 50001
#define DD 128
#define NE 800000
#define EDGE_BLOCKS 3125             // ceil(800000/256)
#define ATT_BLOCKS 3126              // ceil(50001/16)
#define TR_BLOCKS 64                 // transpose blocks (2 cols each)
#define ASTRIDE 136                  // LDS agg row stride in shorts (16B-aligned)

typedef __attribute__((ext_vector_type(8))) short short8;
typedef __attribute__((ext_vector_type(4))) float floatx4;

__device__ __forceinline__ unsigned short f2bf(float f) {
    unsigned u = __builtin_bit_cast(unsigned, f);
    u += 0x7fffu + ((u >> 16) & 1u);          // round-to-nearest-even
    return (unsigned short)(u >> 16);
}
__device__ __forceinline__ float bflo(unsigned u) {   // low 16 bits as bf16 -> f32
    return __builtin_bit_cast(float, u << 16);
}
__device__ __forceinline__ float bfhi(unsigned u) {   // high 16 bits as bf16 -> f32
    return __builtin_bit_cast(float, u & 0xffff0000u);
}
__device__ __forceinline__ float score(float att) {   // leaky-relu(0.2) then exp(x-1)
    att = att >= 0.f ? att : 0.2f * att;
    return __expf(att - 1.f);
}

// K0: bx<64: WT[j][k]=bf16(W[k][j]); bx==64: u/c compute; bx>64: rowptr.
__global__ void __launch_bounds__(256) k_pre(const float* __restrict__ W,
        const float* __restrict__ W_att, const float* __restrict__ b_scale,
        const float* __restrict__ b_att, const int* __restrict__ edge,
        unsigned short* __restrict__ WT, float* __restrict__ u_src,
        float* __restrict__ u_dst, float* __restrict__ cb,
        int* __restrict__ row_ptr) {
    if (blockIdx.x < TR_BLOCKS) {
        int j = blockIdx.x * 2 + (threadIdx.x >> 7);    // feature column
        int k = threadIdx.x & 127;                      // contraction index
        WT[j * DD + k] = f2bf(W[k * DD + j]);
        return;
    }
    if (blockIdx.x == TR_BLOCKS) {                      // u_src/u_dst/c (tiny)
        int k = threadIdx.x;
        if (k < DD) {
            float us = 0.f, ud = 0.f;
            for (int j = 0; j < DD; j++) {
                float w = W[k * DD + j];
                us += w * W_att[j];
                ud += w * W_att[DD + j];
            }
            u_src[k] = us; u_dst[k] = ud;
        } else if (k == DD) {
            float c = b_att[0];
            for (int j = 0; j < DD; j++) c += b_scale[j] * W_att[j];
            cb[0] = c;
        } else if (k == DD + 1) {
            float c = 0.f;
            for (int j = 0; j < DD; j++) c += b_scale[j] * W_att[DD + j];
            cb[1] = c;
        }
        return;
    }
    int e = (blockIdx.x - TR_BLOCKS - 1) * 256 + threadIdx.x;
    if (e >= NE) return;
    int s = edge[2 * e];
    if (e == 0) {
        for (int n = 0; n <= s; n++) row_ptr[n] = 0;
    } else {
        int p = edge[2 * (e - 1)];
        for (int n = p + 1; n <= s; n++) row_ptr[n] = e;
    }
    if (e == NE - 1) {
        for (int n = s + 1; n <= NN; n++) row_ptr[n] = NE;
    }
}

// K1: a_src[n]=emb[n].u_src+c0, a_dst=emb.u_dst+c1, emb_bf=bf16(emb). Unchanged.
__global__ void __launch_bounds__(256) k_att(const float* __restrict__ emb,
        const float* __restrict__ u_src, const float* __restrict__ u_dst,
        const float* __restrict__ cb, unsigned short* __restrict__ emb_bf,
        float* __restrict__ a_src, float* __restrict__ a_dst) {
    int n = blockIdx.x * 16 + (threadIdx.x >> 4);
    int t = threadIdx.x & 15;
    if (n >= NN) return;

    const float* ep = emb + (long)n * DD + t * 8;
    float4 e0 = *(const float4*)(ep);
    float4 e1 = *(const float4*)(ep + 4);
    float4 us0 = *(const float4*)(u_src + t * 8);
    float4 us1 = *(const float4*)(u_src + t * 8 + 4);
    float4 ud0 = *(const float4*)(u_dst + t * 8);
    float4 ud1 = *(const float4*)(u_dst + t * 8 + 4);

    float ps = e0.x * us0.x + e0.y * us0.y + e0.z * us0.z + e0.w * us0.w
             + e1.x * us1.x + e1.y * us1.y + e1.z * us1.z + e1.w * us1.w;
    float pd = e0.x * ud0.x + e0.y * ud0.y + e0.z * ud0.z + e0.w * ud0.w
             + e1.x * ud1.x + e1.y * ud1.y + e1.z * ud1.z + e1.w * ud1.w;

    uint4 pk;
    pk.x = (unsigned)f2bf(e0.x) | ((unsigned)f2bf(e0.y) << 16);
    pk.y = (unsigned)f2bf(e0.z) | ((unsigned)f2bf(e0.w) << 16);
    pk.z = (unsigned)f2bf(e1.x) | ((unsigned)f2bf(e1.y) << 16);
    pk.w = (unsigned)f2bf(e1.z) | ((unsigned)f2bf(e1.w) << 16);
    *(uint4*)(emb_bf + (long)n * DD + t * 8) = pk;

    ps += __shfl_xor(ps, 1, 16); ps += __shfl_xor(ps, 2, 16);
    ps += __shfl_xor(ps, 4, 16); ps += __shfl_xor(ps, 8, 16);
    pd += __shfl_xor(pd, 1, 16); pd += __shfl_xor(pd, 2, 16);
    pd += __shfl_xor(pd, 4, 16); pd += __shfl_xor(pd, 8, 16);
    if (t == 0) { a_src[n] = ps + cb[0]; a_dst[n] = pd + cb[1]; }
}

// K2: fused gather + out-GEMM. 16 nodes/block. Phase A: 16-lane group per node
// gathers emb_bf rows (8-deep pipelined), normalizes, writes bf16 row to LDS.
// Phase B: 4 waves split the 8 feature-chunks; B-frags from LDS, A from WT.
#define ACC8(S, U) \
    acc[0] += (S) * bflo((U).x); acc[1] += (S) * bfhi((U).x); \
    acc[2] += (S) * bflo((U).y); acc[3] += (S) * bfhi((U).y); \
    acc[4] += (S) * bflo((U).z); acc[5] += (S) * bfhi((U).z); \
    acc[6] += (S) * bflo((U).w); acc[7] += (S) * bfhi((U).w);

__global__ void __launch_bounds__(256) k_fused(const int* __restrict__ edge,
        const int* __restrict__ row_ptr, const unsigned short* __restrict__ emb_bf,
        const float* __restrict__ a_src, const float* __restrict__ a_dst,
        const unsigned short* __restrict__ WT, const float* __restrict__ b_scale,
        float* __restrict__ out) {
    __shared__ unsigned short AGG[16 * ASTRIDE];        // 4352 B
    __shared__ int LENS[16];

    int g = threadIdx.x >> 4, t = threadIdx.x & 15;
    int n = blockIdx.x * 16 + g;
    bool nvalid = n < NN;

    int start = 0, len = 0;
    if (nvalid) { start = row_ptr[n]; len = row_ptr[n + 1] - start; }
    if (t == 0) LENS[g] = nvalid ? len : 0;

    uint4 pk = make_uint4(0u, 0u, 0u, 0u);
    if (nvalid && len > 0) {
        float asrc = a_src[n];                 // c_src (incl. b_att) folded in
        const int* dp = edge + 2 * start + 1;  // dst stream, stride-2 ints
        const unsigned short* ip = emb_bf + t * 8;

        float acc[8] = {0.f, 0.f, 0.f, 0.f, 0.f, 0.f, 0.f, 0.f};
        float ssum = 0.f;

        for (int j = 0; j < len; j += 16) {
            int jj = j + t;
            int idx = jj < len ? jj : len - 1;
            int d = dp[2 * idx];               // 16 lanes, contiguous 128 B window
            float x = a_dst[d];                // scattered 4 B, L2-resident
            float s = (jj < len) ? score(asrc + x) : 0.f;
            ssum += s;

            int cnt = len - j;
            if (cnt > 16) cnt = 16;
            int kk = 0;
            for (; kk + 8 <= cnt; kk += 8) {   // 8 gathers in flight
                int d0 = __shfl(d, kk, 16),     d1 = __shfl(d, kk + 1, 16);
                int d2 = __shfl(d, kk + 2, 16), d3 = __shfl(d, kk + 3, 16);
                int d4 = __shfl(d, kk + 4, 16), d5 = __shfl(d, kk + 5, 16);
                int d6 = __shfl(d, kk + 6, 16), d7 = __shfl(d, kk + 7, 16);
                float s0 = __shfl(s, kk, 16),     s1 = __shfl(s, kk + 1, 16);
                float s2 = __shfl(s, kk + 2, 16), s3 = __shfl(s, kk + 3, 16);
                float s4 = __shfl(s, kk + 4, 16), s5 = __shfl(s, kk + 5, 16);
                float s6 = __shfl(s, kk + 6, 16), s7 = __shfl(s, kk + 7, 16);
                uint4 u0 = *(const uint4*)(ip + (long)d0 * DD);
                uint4 u1 = *(const uint4*)(ip + (long)d1 * DD);
                uint4 u2 = *(const uint4*)(ip + (long)d2 * DD);
                uint4 u3 = *(const uint4*)(ip + (long)d3 * DD);
                uint4 u4 = *(const uint4*)(ip + (long)d4 * DD);
                uint4 u5 = *(const uint4*)(ip + (long)d5 * DD);
                uint4 u6 = *(const uint4*)(ip + (long)d6 * DD);
                uint4 u7 = *(const uint4*)(ip + (long)d7 * DD);
                ACC8(s0, u0); ACC8(s1, u1); ACC8(s2, u2); ACC8(s3, u3);
                ACC8(s4, u4); ACC8(s5, u5); ACC8(s6, u6); ACC8(s7, u7);
            }
            for (; kk + 4 <= cnt; kk += 4) {
                int d0 = __shfl(d, kk, 16),     d1 = __shfl(d, kk + 1, 16);
                int d2 = __shfl(d, kk + 2, 16), d3 = __shfl(d, kk + 3, 16);
                float s0 = __shfl(s, kk, 16),     s1 = __shfl(s, kk + 1, 16);
                float s2 = __shfl(s, kk + 2, 16), s3 = __shfl(s, kk + 3, 16);
                uint4 u0 = *(const uint4*)(ip + (long)d0 * DD);
                uint4 u1 = *(const uint4*)(ip + (long)d1 * DD);
                uint4 u2 = *(const uint4*)(ip + (long)d2 * DD);
                uint4 u3 = *(const uint4*)(ip + (long)d3 * DD);
                ACC8(s0, u0); ACC8(s1, u1); ACC8(s2, u2); ACC8(s3, u3);
            }
            for (; kk < cnt; kk++) {
                int d0 = __shfl(d, kk, 16);
                float s0 = __shfl(s, kk, 16);
                uint4 u0 = *(const uint4*)(ip + (long)d0 * DD);
                ACC8(s0, u0);
            }
        }

        ssum += __shfl_xor(ssum, 1, 16);
        ssum += __shfl_xor(ssum, 2, 16);
        ssum += __shfl_xor(ssum, 4, 16);
        ssum += __shfl_xor(ssum, 8, 16);
        float inv = 1.f / ssum;

        pk.x = (unsigned)f2bf(acc[0] * inv) | ((unsigned)f2bf(acc[1] * inv) << 16);
        pk.y = (unsigned)f2bf(acc[2] * inv) | ((unsigned)f2bf(acc[3] * inv) << 16);
        pk.z = (unsigned)f2bf(acc[4] * inv) | ((unsigned)f2bf(acc[5] * inv) << 16);
        pk.w = (unsigned)f2bf(acc[6] * inv) | ((unsigned)f2bf(acc[7] * inv) << 16);
    }
    *(uint4*)(AGG + g * ASTRIDE + t * 8) = pk;          // 16B aligned, 2-way banks
    __syncthreads();

    // ---- Phase B: out = sigmoid(AGG @ W + b_scale); empty nodes -> 0.5 ----
    int wave = threadIdx.x >> 6;                        // ft pair = wave*2, wave*2+1
    int lane = threadIdx.x & 63;
    int m = lane & 15, q = lane >> 4;
    int node = blockIdx.x * 16 + m;
    bool valid = node < NN;
    int lenm = LENS[m];

    short8 b[4];
    #pragma unroll
    for (int ks = 0; ks < 4; ks++)
        b[ks] = *(const short8*)(AGG + m * ASTRIDE + ks * 32 + q * 8);

    #pragma unroll
    for (int f2 = 0; f2 < 2; f2++) {
        int ft = wave * 2 + f2;
        floatx4 acc = {0.f, 0.f, 0.f, 0.f};
        const unsigned short* wrow = WT + (ft * 16 + m) * DD + q * 8;
        #pragma unroll
        for (int ks = 0; ks < 4; ks++) {
            short8 a = *(const short8*)(wrow + ks * 32);
            acc = __builtin_amdgcn_mfma_f32_16x16x32_bf16(a, b[ks], acc, 0, 0, 0);
        }
        if (valid) {
            int fo = ft * 16 + q * 4;
            float4 bs = *(const float4*)(b_scale + fo);
            float4 o;
            if (lenm > 0) {
                o.x = 1.f / (1.f + __expf(-(acc[0] + bs.x)));
                o.y = 1.f / (1.f + __expf(-(acc[1] + bs.y)));
                o.z = 1.f / (1.f + __expf(-(acc[2] + bs.z)));
                o.w = 1.f / (1.f + __expf(-(acc[3] + bs.w)));
            } else {
                o = make_float4(0.5f, 0.5f, 0.5f, 0.5f);
            }
            *(float4*)(out + (long)node * DD + fo) = o;
        }
    }
}

extern "C" void kernel_launch(void* const* d_in, const int* in_sizes, int n_in,
                              void* d_out, int out_size, void* d_ws, size_t ws_size,
                              hipStream_t stream) {
    const int*   edge    = (const int*)d_in[0];
    const float* emb     = (const float*)d_in[1];
    const float* W_scale = (const float*)d_in[2];
    const float* b_scale = (const float*)d_in[3];
    const float* W_att   = (const float*)d_in[4];
    const float* b_att   = (const float*)d_in[5];
    float* out = (float*)d_out;

    char* ws = (char*)d_ws;
    int*            row_ptr = (int*)(ws);                                // 200832 B
    float*          a_src   = (float*)(ws + 200832);                     // 200192 B
    float*          a_dst   = (float*)(ws + 401024);                     // 200192 B
    unsigned short* emb_bf  = (unsigned short*)(ws + 601216);            // 12800256 B
    unsigned short* WT      = (unsigned short*)(ws + 13401472);          // 32768 B
    float*          u_src   = (float*)(ws + 13434240);                   // 512 B
    float*          u_dst   = (float*)(ws + 13434752);                   // 512 B
    float*          cb      = (float*)(ws + 13435264);                   // 8 B

    k_pre   <<<TR_BLOCKS + 1 + EDGE_BLOCKS, 256, 0, stream>>>(W_scale, W_att, b_scale,
                                                              b_att, edge, WT, u_src,
                                                              u_dst, cb, row_ptr);
    k_att   <<<ATT_BLOCKS, 256, 0, stream>>>(emb, u_src, u_dst, cb, emb_bf,
                                             a_src, a_dst);
    k_fused <<<ATT_BLOCKS, 256, 0, stream>>>(edge, row_ptr, emb_bf, a_src, a_dst,
                                             WT, b_scale, out);
}